// Round 10
// baseline (785.933 us; speedup 1.0000x reference)
//
#include <hip/hip_runtime.h>
#include <hip/hip_bf16.h>

#define HDIM 128
#define NREL 16
#define NBASES 8
#define KSLOTS 17            // 16 relations + self-loop
#define KDIM (KSLOTS * HDIM) // 2176
#define TROWS 32             // rows per tile/block
#define ELCAP 1024           // per-block LDS edge cache (mean 512, +22 sigma)

typedef short bf16x8 __attribute__((ext_vector_type(8)));
typedef short s16x4 __attribute__((ext_vector_type(4)));
typedef float f32x4 __attribute__((ext_vector_type(4)));

static __device__ __forceinline__ short f2bf(float x) {
    __hip_bfloat16 b = __float2bfloat16(x);
    return *(short*)&b;
}
static __device__ __forceinline__ float bf2f(short u) {
    unsigned v = ((unsigned)(unsigned short)u) << 16;
    return __uint_as_float(v);
}

// ---------------- weight prep ----------------
// wtL[o][r*128+i] = W_r[i][o] = sum_b wcomp[r][b]*basis[b][i][o]   (bf16)
__global__ void compute_wt(const float* __restrict__ basis,
                           const float* __restrict__ wcomp,
                           short* __restrict__ wtL) {
    int ro = blockIdx.x;
    int r = ro >> 7, o = ro & 127;
    int i = threadIdx.x;
    float acc = 0.f;
#pragma unroll
    for (int b = 0; b < NBASES; ++b)
        acc += wcomp[r * NBASES + b] * basis[(b * HDIM + i) * HDIM + o];
    wtL[(size_t)o * KDIM + r * HDIM + i] = f2bf(acc);
}

// wtL[o][2048+i] = loop_w[i][o]
__global__ void transposeL(const float* __restrict__ in, short* __restrict__ wtL) {
    int o = blockIdx.x, i = threadIdx.x;
    wtL[(size_t)o * KDIM + NREL * HDIM + i] = f2bf(in[i * HDIM + o]);
}

// fp32 -> bf16 cast (vectorized)
__global__ void cast_bf16(const float* __restrict__ in, short* __restrict__ out, int n4) {
    for (int i = blockIdx.x * blockDim.x + threadIdx.x; i < n4; i += gridDim.x * blockDim.x) {
        f32x4 v = ((const f32x4*)in)[i];
        s16x4 o;
#pragma unroll
        for (int j = 0; j < 4; ++j) o[j] = f2bf(v[j]);
        ((s16x4*)out)[i] = o;
    }
}

__global__ void zero_i32(int* __restrict__ p, int n) {
    int i = blockIdx.x * blockDim.x + threadIdx.x;
    if (i < n) p[i] = 0;
}

// ---- counting sort by key = ((dst>>5)*16 + rel)*32 + (dst&31)  (~800K bins) ----
// Groups edges of (32-row tile, relation) contiguously, sorted by local row:
// exactly the access order of the fused kernel's per-slot build phase.
__global__ __launch_bounds__(256) void hist_k(const int* __restrict__ dst,
                                              const int* __restrict__ rel, int n,
                                              int* __restrict__ hist) {
    for (int i = blockIdx.x * blockDim.x + threadIdx.x; i < n; i += gridDim.x * blockDim.x) {
        int d = dst[i];
        int k = (((d >> 5) * NREL + rel[i]) << 5) | (d & 31);
        atomicAdd(&hist[k], 1);
    }
}

__global__ __launch_bounds__(1024) void scan_p1(const int* __restrict__ hist, int n,
                                                int* __restrict__ off, int* __restrict__ part) {
    __shared__ int sh[1024];
    int t = threadIdx.x, b = blockIdx.x;
    int i = b * 1024 + t;
    int x = (i < n) ? hist[i] : 0;
    sh[t] = x;
    __syncthreads();
    for (int d = 1; d < 1024; d <<= 1) {
        int v = sh[t];
        int u = (t >= d) ? sh[t - d] : 0;
        __syncthreads();
        sh[t] = v + u;
        __syncthreads();
    }
    if (i < n) off[i] = sh[t] - x;
    if (t == 1023) part[b] = sh[t];
}

__global__ __launch_bounds__(1024) void scan_p2(int* __restrict__ part, int nb) {
    __shared__ int sh[1024];
    int t = threadIdx.x;
    int x = (t < nb) ? part[t] : 0;
    sh[t] = x;
    __syncthreads();
    for (int d = 1; d < 1024; d <<= 1) {
        int v = sh[t];
        int u = (t >= d) ? sh[t - d] : 0;
        __syncthreads();
        sh[t] = v + u;
        __syncthreads();
    }
    if (t < nb) part[t] = sh[t] - x;
}

__global__ __launch_bounds__(1024) void scan_p3(int* __restrict__ off, const int* __restrict__ part,
                                                int n, int nk, int* __restrict__ cur) {
    int i = blockIdx.x * 1024 + threadIdx.x;
    if (i < n) {
        int v = off[i] + part[blockIdx.x];
        off[i] = v;
        if (i < nk) cur[i] = v;
    }
}

// place edges: edge2[p] = src (global entity id)
__global__ __launch_bounds__(256) void scatter_k(const int* __restrict__ src,
                                                 const int* __restrict__ dst,
                                                 const int* __restrict__ rel, int n,
                                                 int* __restrict__ cur,
                                                 int* __restrict__ edge2) {
    for (int i = blockIdx.x * blockDim.x + threadIdx.x; i < n; i += gridDim.x * blockDim.x) {
        int d = dst[i];
        int k = (((d >> 5) * NREL + rel[i]) << 5) | (d & 31);
        int p = atomicAdd(&cur[k], 1);
        edge2[p] = src[i];
    }
}

// ---------------- fused layer: out = relu([agg_r|h] @ WstackT + bias) ----------------
// Block = 32 output rows, 128 threads (2 waves x 64 cols; 8 gather-groups x 16
// lanes, group g owns rows 4g..4g+3). No AGG materialization: per slot ks the
// group gathers its rows' h[src] edges (contiguous in the key-sorted edge list,
// cached in LDS) into registers, fp32-accumulates, and writes one bf16 row into
// the XOR-swizzled LDS A-buffer (zeros for empty rows). Double-buffered:
//   per slot: [load B(k) frags] [issue gathers(k+1)] [MFMA(k)] [consume->ds_write
//   A(k+1)] [barrier]   — nothing is in flight at the barrier (drain is free),
// gather latency hides under MFMA+consume, B waits chain behind nothing slower.
__global__ __launch_bounds__(128, 3) void rgcn_fused(
    const short* __restrict__ h,      // bf16 [N][128]
    const short* __restrict__ wtL,    // [128 o][2176 k] bf16
    const int* __restrict__ off2,     // [ntiles*512 + 1]
    const int* __restrict__ edge2,    // src per edge, key-sorted
    const float* __restrict__ bias,   // [128]
    short* __restrict__ out_bf,       // layer-1 output (bf16) or nullptr
    float* __restrict__ out_f,        // layer-2 output (fp32) or nullptr
    int n) {
    __shared__ short A0[TROWS * HDIM];   // 8 KB
    __shared__ short A1[TROWS * HDIM];   // 8 KB
    __shared__ int sOff[NREL * TROWS + 1]; // 513 offsets
    __shared__ int elist[ELCAP];

    int tid = threadIdx.x;
    int tile = blockIdx.x;
    int row0 = tile * TROWS;
    int wave = tid >> 6, lane = tid & 63;
    int nq = wave * 64;
    int lr = lane & 15, quad = lane >> 4;
    int g = tid >> 4, l16 = tid & 15;

    // ---- prologue: offsets + edge srcs into LDS (coalesced, once) ----
    for (int i = tid; i <= NREL * TROWS; i += 128) sOff[i] = off2[tile * (NREL * TROWS) + i];
    __syncthreads();
    int base = sOff[0];
    int tot = sOff[NREL * TROWS] - base;
    for (int i = tid; i < tot && i < ELCAP; i += 128) elist[i] = edge2[base + i];
    __syncthreads();

    // ---- gather state: group g, rows 4g..4g+3, up to 2 preloaded edges/row ----
    bf16x8 va[4][2];
    int dg[4], ebeg[4];

    auto issue = [&](int ks) {
#pragma unroll
        for (int ri = 0; ri < 4; ++ri) {
            int r = g * 4 + ri;
            if (ks == NREL) {                 // self-loop slot
                int gr = row0 + r;
                dg[ri] = (gr < n) ? 1 : 0;
                ebeg[ri] = 0;
                if (gr < n) va[ri][0] = *(const bf16x8*)(h + (size_t)gr * HDIM + l16 * 8);
            } else {
                int a = sOff[ks * TROWS + r], b = sOff[ks * TROWS + r + 1];
                dg[ri] = b - a;
                ebeg[ri] = a - base;
#pragma unroll
                for (int j = 0; j < 2; ++j) {
                    if (j < b - a) {
                        int e = a - base + j;
                        int s = (e < ELCAP) ? elist[e] : edge2[base + e];
                        va[ri][j] = *(const bf16x8*)(h + (size_t)s * HDIM + l16 * 8);
                    }
                }
            }
        }
    };
    auto consume = [&](short* buf) {
#pragma unroll
        for (int ri = 0; ri < 4; ++ri) {
            int r = g * 4 + ri;
            short* dp = buf + r * HDIM + ((l16 ^ (r & 7)) * 8);   // swizzled store
            int d = dg[ri];
            if (d <= 0) {
                *(bf16x8*)dp = (bf16x8)0;
            } else if (d == 1) {
                *(bf16x8*)dp = va[ri][0];
            } else {
                float ac[8];
#pragma unroll
                for (int c = 0; c < 8; ++c) ac[c] = bf2f(va[ri][0][c]) + bf2f(va[ri][1][c]);
                for (int j = 2; j < d; ++j) {          // rare: deg > 2 (P~0.08)
                    int e = ebeg[ri] + j;
                    int s = (e < ELCAP) ? elist[e] : edge2[base + e];
                    bf16x8 v = *(const bf16x8*)(h + (size_t)s * HDIM + l16 * 8);
#pragma unroll
                    for (int c = 0; c < 8; ++c) ac[c] += bf2f(v[c]);
                }
                bf16x8 o;
#pragma unroll
                for (int c = 0; c < 8; ++c) o[c] = f2bf(ac[c]);
                *(bf16x8*)dp = o;
            }
        }
    };

    // slot 0 build (no overlap available for the first tile)
    issue(0);
    consume(A0);
    __syncthreads();

    f32x4 acc[2][4] = {};
    const short* wb = wtL + (size_t)(nq + lr) * KDIM;

#pragma unroll 1
    for (int ks = 0; ks < KSLOTS; ++ks) {
        short* Ab = (ks & 1) ? A1 : A0;
        short* An = (ks & 1) ? A0 : A1;

        // B fragments for this slot, issued first (L2-hot; nothing older in flight)
        bf16x8 br[4][4];
#pragma unroll
        for (int kk = 0; kk < 4; ++kk)
#pragma unroll
            for (int ni = 0; ni < 4; ++ni)
                br[kk][ni] = *(const bf16x8*)(wb + (size_t)ni * 16 * KDIM + ks * HDIM + kk * 32 + quad * 8);

        // issue next slot's gathers now; they complete under MFMA+consume
        if (ks + 1 < KSLOTS) issue(ks + 1);

        // MFMA slot ks (swizzled A reads: conflict-free)
#pragma unroll
        for (int kk = 0; kk < 4; ++kk) {
            bf16x8 a2[2];
#pragma unroll
            for (int mi = 0; mi < 2; ++mi) {
                int r = mi * 16 + lr;
                int ch = (kk * 4 + quad) ^ (r & 7);
                a2[mi] = *(const bf16x8*)(Ab + r * HDIM + ch * 8);
            }
#pragma unroll
            for (int mi = 0; mi < 2; ++mi)
#pragma unroll
                for (int ni = 0; ni < 4; ++ni)
                    acc[mi][ni] = __builtin_amdgcn_mfma_f32_16x16x32_bf16(a2[mi], br[kk][ni], acc[mi][ni], 0, 0, 0);
        }

        // build next slot's A tile (writes the OTHER buffer; no race with MFMA)
        if (ks + 1 < KSLOTS) consume(An);

        __syncthreads();   // nothing in flight: drain is free
    }

    // epilogue: bias + relu, single store.  C/D: col=lane&15, row=quad*4+reg [m89]
#pragma unroll
    for (int mi = 0; mi < 2; ++mi) {
#pragma unroll
        for (int reg = 0; reg < 4; ++reg) {
            int gr = row0 + mi * 16 + quad * 4 + reg;
            if (gr < n) {
                size_t gd = (size_t)gr * HDIM;
#pragma unroll
                for (int ni = 0; ni < 4; ++ni) {
                    int nn = nq + ni * 16 + lr;
                    float v = acc[mi][ni][reg] + bias[nn];
                    v = v > 0.f ? v : 0.f;
                    if (out_bf) out_bf[gd + nn] = f2bf(v);
                    else        out_f[gd + nn] = v;
                }
            }
        }
    }
}

extern "C" void kernel_launch(void* const* d_in, const int* in_sizes, int n_in,
                              void* d_out, int out_size, void* d_ws, size_t ws_size,
                              hipStream_t stream) {
    const float* emb    = (const float*)d_in[0];
    const float* basis1 = (const float*)d_in[1];
    const float* wc1    = (const float*)d_in[2];
    const float* lw1    = (const float*)d_in[3];
    const float* bias1  = (const float*)d_in[4];
    const float* basis2 = (const float*)d_in[5];
    const float* wc2    = (const float*)d_in[6];
    const float* lw2    = (const float*)d_in[7];
    const float* bias2  = (const float*)d_in[8];
    const int* src = (const int*)d_in[9];
    const int* dst = (const int*)d_in[10];
    const int* rel = (const int*)d_in[11];

    int n_ent = in_sizes[0] / HDIM;
    int n_edges = in_sizes[9];
    int ntiles = (n_ent + TROWS - 1) / TROWS;
    int NK = ntiles * NREL * TROWS;   // bins
    int NK1 = NK + 1;

    char* ws = (char*)d_ws;
    size_t wo = 0;
    auto alloc = [&](size_t bytes) {
        void* p = ws + wo;
        wo = (wo + bytes + 255) & ~(size_t)255;
        return p;
    };
    int* hist  = (int*)alloc((size_t)NK1 * 4);
    int* off2  = (int*)alloc((size_t)NK1 * 4);
    int* cur   = (int*)alloc((size_t)NK * 4);
    int* part  = (int*)alloc(4096);
    int* edge2 = (int*)alloc((size_t)n_edges * 4);
    short* wtL1 = (short*)alloc((size_t)HDIM * KDIM * 2);
    short* wtL2 = (short*)alloc((size_t)HDIM * KDIM * 2);
    short* h0   = (short*)alloc((size_t)n_ent * HDIM * 2);
    short* h1   = (short*)alloc((size_t)n_ent * HDIM * 2);

    // weight prep + input cast
    compute_wt<<<NREL * HDIM, HDIM, 0, stream>>>(basis1, wc1, wtL1);
    compute_wt<<<NREL * HDIM, HDIM, 0, stream>>>(basis2, wc2, wtL2);
    transposeL<<<HDIM, HDIM, 0, stream>>>(lw1, wtL1);
    transposeL<<<HDIM, HDIM, 0, stream>>>(lw2, wtL2);
    cast_bf16<<<512, 256, 0, stream>>>(emb, h0, n_ent * HDIM / 4);

    // counting sort (once; reused by both layers)
    zero_i32<<<(NK1 + 255) / 256, 256, 0, stream>>>(hist, NK1);
    hist_k<<<1024, 256, 0, stream>>>(dst, rel, n_edges, hist);
    int nsb = (NK1 + 1023) / 1024;
    scan_p1<<<nsb, 1024, 0, stream>>>(hist, NK1, off2, part);
    scan_p2<<<1, 1024, 0, stream>>>(part, nsb);
    scan_p3<<<nsb, 1024, 0, stream>>>(off2, part, NK1, NK, cur);
    scatter_k<<<1024, 256, 0, stream>>>(src, dst, rel, n_edges, cur, edge2);

    // fused layers: no AGG materialization, no atomics, single store per output
    rgcn_fused<<<ntiles, 128, 0, stream>>>(h0, wtL1, off2, edge2, bias1,
                                           h1, nullptr, n_ent);
    rgcn_fused<<<ntiles, 128, 0, stream>>>(h1, wtL2, off2, edge2, bias2,
                                           nullptr, (float*)d_out, n_ent);
}

// Round 11
// 504.323 us; speedup vs baseline: 1.5584x; 1.5584x over previous
//
#include <hip/hip_runtime.h>
#include <hip/hip_bf16.h>

#define HDIM 128
#define NREL 16
#define NBASES 8
#define KSLOTS 17            // 16 relations + self-loop (weights only)
#define KDIM (KSLOTS * HDIM) // 2176
#define LDSA 136             // bf16 LDS row stride (128+8): 2-way alias, free (m136)

typedef short bf16x8 __attribute__((ext_vector_type(8)));
typedef short s16x4 __attribute__((ext_vector_type(4)));
typedef float f32x4 __attribute__((ext_vector_type(4)));

static __device__ __forceinline__ short f2bf(float x) {
    __hip_bfloat16 b = __float2bfloat16(x);
    return *(short*)&b;
}
static __device__ __forceinline__ float bf2f(short u) {
    unsigned v = ((unsigned)(unsigned short)u) << 16;
    return __uint_as_float(v);
}

// ---------------- weight prep ----------------
// wtL[o][r*128+i] = W_r[i][o] = sum_b wcomp[r][b]*basis[b][i][o]   (bf16)
__global__ void compute_wt(const float* __restrict__ basis,
                           const float* __restrict__ wcomp,
                           short* __restrict__ wtL) {
    int ro = blockIdx.x;
    int r = ro >> 7, o = ro & 127;
    int i = threadIdx.x;
    float acc = 0.f;
#pragma unroll
    for (int b = 0; b < NBASES; ++b)
        acc += wcomp[r * NBASES + b] * basis[(b * HDIM + i) * HDIM + o];
    wtL[(size_t)o * KDIM + r * HDIM + i] = f2bf(acc);
}

// wtL[o][2048+i] = loop_w[i][o]
__global__ void transposeL(const float* __restrict__ in, short* __restrict__ wtL) {
    int o = blockIdx.x, i = threadIdx.x;
    wtL[(size_t)o * KDIM + NREL * HDIM + i] = f2bf(in[i * HDIM + o]);
}

// fp32 -> bf16 cast (vectorized)
__global__ void cast_bf16(const float* __restrict__ in, short* __restrict__ out, int n4) {
    for (int i = blockIdx.x * blockDim.x + threadIdx.x; i < n4; i += gridDim.x * blockDim.x) {
        f32x4 v = ((const f32x4*)in)[i];
        s16x4 o;
#pragma unroll
        for (int j = 0; j < 4; ++j) o[j] = f2bf(v[j]);
        ((s16x4*)out)[i] = o;
    }
}

__global__ void zero_i32(int* __restrict__ p, int n) {
    int i = blockIdx.x * blockDim.x + threadIdx.x;
    if (i < n) p[i] = 0;
}

// ---------------- counting sort by key = dst*16 + rel (800K bins) ----------------
__global__ __launch_bounds__(256) void hist_k(const int* __restrict__ dst,
                                              const int* __restrict__ rel, int n,
                                              int* __restrict__ hist) {
    for (int i = blockIdx.x * blockDim.x + threadIdx.x; i < n; i += gridDim.x * blockDim.x)
        atomicAdd(&hist[dst[i] * NREL + rel[i]], 1);
}

// thr==0: scan raw counts; thr>0: scan indicator (count >= thr)
__global__ __launch_bounds__(1024) void scan_p1(const int* __restrict__ hist, int n,
                                                int* __restrict__ off, int* __restrict__ part,
                                                int thr) {
    __shared__ int sh[1024];
    int t = threadIdx.x, b = blockIdx.x;
    int i = b * 1024 + t;
    int x = (i < n) ? hist[i] : 0;
    if (thr) x = (x >= thr) ? 1 : 0;
    sh[t] = x;
    __syncthreads();
    for (int d = 1; d < 1024; d <<= 1) {
        int v = sh[t];
        int u = (t >= d) ? sh[t - d] : 0;
        __syncthreads();
        sh[t] = v + u;
        __syncthreads();
    }
    if (i < n) off[i] = sh[t] - x;
    if (t == 1023) part[b] = sh[t];
}

__global__ __launch_bounds__(1024) void scan_p2(int* __restrict__ part, int nb) {
    __shared__ int sh[1024];
    int t = threadIdx.x;
    int x = (t < nb) ? part[t] : 0;
    sh[t] = x;
    __syncthreads();
    for (int d = 1; d < 1024; d <<= 1) {
        int v = sh[t];
        int u = (t >= d) ? sh[t - d] : 0;
        __syncthreads();
        sh[t] = v + u;
        __syncthreads();
    }
    if (t < nb) part[t] = sh[t] - x;
}

__global__ __launch_bounds__(1024) void scan_p3(int* __restrict__ off, const int* __restrict__ part,
                                                int n, int nk, int* __restrict__ cur) {
    int i = blockIdx.x * 1024 + threadIdx.x;
    if (i < n) {
        int v = off[i] + part[blockIdx.x];
        off[i] = v;
        if (i < nk) cur[i] = v;
    }
}

// place edges: edge2[p] = src | rel<<16  (n_ent < 65536)
__global__ __launch_bounds__(256) void scatter_k(const int* __restrict__ src,
                                                 const int* __restrict__ dst,
                                                 const int* __restrict__ rel, int n,
                                                 int* __restrict__ cur,
                                                 int* __restrict__ edge2) {
    for (int i = blockIdx.x * blockDim.x + threadIdx.x; i < n; i += gridDim.x * blockDim.x) {
        int k = dst[i] * NREL + rel[i];
        int p = atomicAdd(&cur[k], 1);
        edge2[p] = (src[i] & 0xFFFF) | (rel[i] << 16);
    }
}

// ---------------- AGG build: exact-classified, compact output ----------------
// Group = 16 lanes per (dst row, 8-slot rel-half). Per-slot deg is EXACT
// (from off[]); multi slots (deg>=2) write their fp32-accumulated aggregate
// to the COMPACT array AGGc at precomputed index off2m[k] (dense, bin-order
// = row-major by dst -> L3/L2-friendly). Slot codes (u32):
//   0xFFFFFFFF = empty; 0x80000000|idx = multi (AGGc row); else = single src.
// No barriers, no atomics, no zero-fill.
__global__ __launch_bounds__(256) void agg_build(
    const short* __restrict__ h,
    const int* __restrict__ off,      // [NK+1] bin offsets
    const int* __restrict__ off2m,    // [NK+1] compact-index scan of (cnt>=2)
    const int* __restrict__ edge2,    // src | rel<<16, key-sorted
    short* __restrict__ AGGc,         // compact [nMulti][128] bf16
    unsigned* __restrict__ srcs,      // [rows][16] slot codes
    int rows) {
    int tid = threadIdx.x;
    int grp = blockIdx.x * 16 + (tid >> 4);
    int lane16 = tid & 15;
    int lane = tid & 63;
    int gb = lane & 48;               // 16-lane group base within wave
    int drow = grp >> 1;
    if (drow >= rows) return;
    int rh = (grp & 1) * 8;
    int kbase = drow * NREL + rh;

    int offv = (lane16 < 9) ? off[kbase + lane16] : 0;
    int cmv  = (lane16 < 8) ? off2m[kbase + lane16] : 0;
    int e0 = __shfl(offv, gb);
    int e8 = __shfl(offv, gb + 8);
    int deg = e8 - e0;
    // per-slot degree (meaningful for lane16<8)
    int nl = gb + ((lane16 < 8) ? lane16 + 1 : 0);
    int degS = __shfl(offv, nl) - offv;

    // window: first 16 edges, replicated to all group lanes
    int pkv = (e0 + lane16 < e8) ? edge2[e0 + lane16] : 0;
    int rlv[16], srcv[16], mul[16];
#pragma unroll
    for (int p = 0; p < 16; ++p) {
        int pk = __shfl(pkv, gb + p);
        int sl = ((pk >> 16) & 15) - rh;
        rlv[p] = (p < deg) ? sl : 0;
        srcv[p] = pk & 0xFFFF;
        int ds = __shfl(degS, gb + rlv[p]);
        mul[p] = (p < deg) && (ds >= 2);
    }

    // gather only multi-slot edges (ILP batch)
    bf16x8 va[16];
#pragma unroll
    for (int p = 0; p < 16; ++p)
        if (mul[p])
            va[p] = *(const bf16x8*)(h + (size_t)srcv[p] * HDIM + lane16 * 8);

    // slot code for lane l<8 (owns slot l)
    unsigned val = 0xFFFFFFFFu;
    if (lane16 < 8) {
        if (degS >= 2) val = 0x80000000u | (unsigned)cmv;
        else if (degS == 1) {
            int ps = offv - e0;            // position of the single edge
            if (ps < 16) {
#pragma unroll
                for (int p = 0; p < 16; ++p) if (ps == p) val = (unsigned)srcv[p];
            } else {
                val = (unsigned)(edge2[e0 + ps] & 0xFFFF);
            }
        }
    }

    // streaming accumulate of multi slots (edges sorted by slot)
    float acc[8] = {0.f, 0.f, 0.f, 0.f, 0.f, 0.f, 0.f, 0.f};
    int cs = -1;
    auto emit = [&]() {
        int cmS = __shfl(cmv, gb + cs);    // group-uniform compact index
        bf16x8 o;
#pragma unroll
        for (int c = 0; c < 8; ++c) o[c] = f2bf(acc[c]);
        *(bf16x8*)(AGGc + (size_t)cmS * HDIM + lane16 * 8) = o;
    };
    auto take = [&](int sl, bf16x8 v) {
        if (sl != cs) {
            if (cs >= 0) emit();
            cs = sl;
#pragma unroll
            for (int c = 0; c < 8; ++c) acc[c] = 0.f;
        }
#pragma unroll
        for (int c = 0; c < 8; ++c) acc[c] += bf2f(v[c]);
    };

#pragma unroll
    for (int p = 0; p < 16; ++p)
        if (mul[p]) take(rlv[p], va[p]);

    // tail: deg > 16 (rare). group-uniform loop bound; shfls stay in-group.
    for (int e = e0 + 16; e < e8; ++e) {
        int pk = edge2[e];
        int sl = ((pk >> 16) & 15) - rh;
        int ds = __shfl(degS, gb + sl);
        if (ds >= 2) {
            bf16x8 v = *(const bf16x8*)(h + (size_t)(pk & 0xFFFF) * HDIM + lane16 * 8);
            take(sl, v);
        }
    }
    if (cs >= 0) emit();

    if (lane16 < 8) srcs[(size_t)drow * NREL + rh + lane16] = val;
}

// ---------------- dense GEMM: out = relu([AGGc|h] @ WstackT + bias) ----------------
// Block = 64 rows x 128 cols, 256 threads (4 waves, wave-tile 32x64).
// R5-proven structure: A and B reg-prefetched one slot ahead (global loads
// issue before slot-k MFMAs -> latency hides under compute), then written to
// padded LDS. A-source per (row,slot) from u32 code: empty -> zeros (no
// read); single -> h[src]; multi -> compact AGGc row (L3-resident now).
// ks==16 self-loop reads h[own row]. 52KB LDS -> 3 blocks/CU.
__global__ __launch_bounds__(256, 3) void agg_gemm(
    const short* __restrict__ AGGc,   // compact [nMulti][128] bf16
    const short* __restrict__ h,      // bf16 [N][128]
    const short* __restrict__ wtL,    // [128 o][2176 k] bf16
    const unsigned* __restrict__ srcs,// [rows][16]
    const float* __restrict__ bias,   // [128]
    short* __restrict__ out_bf,       // layer-1 output (bf16) or nullptr
    float* __restrict__ out_f,        // layer-2 output (fp32) or nullptr
    int rows) {
    __shared__ short As[64 * LDSA];
    __shared__ short Bs[128 * LDSA];
    int tid = threadIdx.x;
    int row0 = blockIdx.x * 64;
    if (row0 >= rows) return;
    int wave = tid >> 6, lane = tid & 63;
    int mq = (wave & 1) * 32, nq = (wave >> 1) * 64;
    int lr = lane & 15, quad = lane >> 4;

    // staging maps
    int r2 = tid >> 2, ca = (tid & 3) * 32;   // A: row r2, 32-short quarter
    int rb = tid >> 1, hb = (tid & 1) * 64;   // B: row rb, 64-short half
    bool ok = (row0 + r2) < rows;

    // preload this row's 16 slot codes
    unsigned cq[16];
    {
        uint4 f4 = make_uint4(0xFFFFFFFFu, 0xFFFFFFFFu, 0xFFFFFFFFu, 0xFFFFFFFFu);
        uint4 v0 = f4, v1 = f4, v2 = f4, v3 = f4;
        if (ok) {
            const uint4* p = (const uint4*)(srcs + (size_t)(row0 + r2) * NREL);
            v0 = p[0]; v1 = p[1]; v2 = p[2]; v3 = p[3];
        }
        cq[0] = v0.x; cq[1] = v0.y; cq[2] = v0.z; cq[3] = v0.w;
        cq[4] = v1.x; cq[5] = v1.y; cq[6] = v1.z; cq[7] = v1.w;
        cq[8] = v2.x; cq[9] = v2.y; cq[10] = v2.z; cq[11] = v2.w;
        cq[12] = v3.x; cq[13] = v3.y; cq[14] = v3.z; cq[15] = v3.w;
    }

    bf16x8 apf[4], bpf[8];
    auto loadRegs = [&](int ks) {
        const short* bp = wtL + (size_t)rb * KDIM + ks * HDIM + hb;
#pragma unroll
        for (int j = 0; j < 8; ++j) bpf[j] = *(const bf16x8*)(bp + j * 8);
        unsigned e;
        if (ks == 16) {
            e = ok ? (unsigned)(row0 + r2) : 0xFFFFFFFFu;   // self-loop: h row
        } else {
            e = 0xFFFFFFFFu;
#pragma unroll
            for (int q = 0; q < 16; ++q) if (ks == q) e = cq[q];  // static select
        }
        if (e == 0xFFFFFFFFu) {
#pragma unroll
            for (int j = 0; j < 4; ++j) apf[j] = (bf16x8)0;
        } else {
            const short* sp = (e & 0x80000000u)
                ? AGGc + (size_t)(e & 0x7FFFFFFFu) * HDIM + ca
                : h + (size_t)e * HDIM + ca;
#pragma unroll
            for (int j = 0; j < 4; ++j) apf[j] = *(const bf16x8*)(sp + j * 8);
        }
    };
    auto writeLDS = [&]() {
        short* ad = As + r2 * LDSA + ca;
#pragma unroll
        for (int j = 0; j < 4; ++j) *(bf16x8*)(ad + j * 8) = apf[j];
        short* bd = Bs + rb * LDSA + hb;
#pragma unroll
        for (int j = 0; j < 8; ++j) *(bf16x8*)(bd + j * 8) = bpf[j];
    };

    f32x4 acc[2][4] = {};

    loadRegs(0);
    writeLDS();
    __syncthreads();

#pragma unroll 1
    for (int ks = 0; ks <= 16; ++ks) {
        if (ks < 16) loadRegs(ks + 1);   // prefetch next slot; hides under MFMA
#pragma unroll
        for (int kk = 0; kk < 4; ++kk) {
            int kb = kk * 32 + quad * 8;
            bf16x8 a2[2], b4[4];
#pragma unroll
            for (int mi = 0; mi < 2; ++mi)
                a2[mi] = *(const bf16x8*)(As + (mq + mi * 16 + lr) * LDSA + kb);
#pragma unroll
            for (int ni = 0; ni < 4; ++ni)
                b4[ni] = *(const bf16x8*)(Bs + (nq + ni * 16 + lr) * LDSA + kb);
#pragma unroll
            for (int mi = 0; mi < 2; ++mi)
#pragma unroll
                for (int ni = 0; ni < 4; ++ni)
                    acc[mi][ni] = __builtin_amdgcn_mfma_f32_16x16x32_bf16(a2[mi], b4[ni], acc[mi][ni], 0, 0, 0);
        }
        __syncthreads();                 // LDS reads done; prefetch arrived
        if (ks < 16) { writeLDS(); __syncthreads(); }
    }

    // epilogue: bias + relu, single store.  C/D: col=lane&15, row=quad*4+reg [m89]
#pragma unroll
    for (int mi = 0; mi < 2; ++mi) {
#pragma unroll
        for (int reg = 0; reg < 4; ++reg) {
            int g = row0 + mq + mi * 16 + quad * 4 + reg;
            if (g < rows) {
                size_t gd = (size_t)g * HDIM;
#pragma unroll
                for (int ni = 0; ni < 4; ++ni) {
                    int n = nq + ni * 16 + lr;
                    float v = acc[mi][ni][reg] + bias[n];
                    v = v > 0.f ? v : 0.f;
                    if (out_bf) out_bf[gd + n] = f2bf(v);
                    else        out_f[gd + n] = v;
                }
            }
        }
    }
}

extern "C" void kernel_launch(void* const* d_in, const int* in_sizes, int n_in,
                              void* d_out, int out_size, void* d_ws, size_t ws_size,
                              hipStream_t stream) {
    const float* emb    = (const float*)d_in[0];
    const float* basis1 = (const float*)d_in[1];
    const float* wc1    = (const float*)d_in[2];
    const float* lw1    = (const float*)d_in[3];
    const float* bias1  = (const float*)d_in[4];
    const float* basis2 = (const float*)d_in[5];
    const float* wc2    = (const float*)d_in[6];
    const float* lw2    = (const float*)d_in[7];
    const float* bias2  = (const float*)d_in[8];
    const int* src = (const int*)d_in[9];
    const int* dst = (const int*)d_in[10];
    const int* rel = (const int*)d_in[11];

    int n_ent = in_sizes[0] / HDIM;
    int n_edges = in_sizes[9];
    int NK = n_ent * NREL;
    int NK1 = NK + 1;

    char* ws = (char*)d_ws;
    size_t wo = 0;
    auto alloc = [&](size_t bytes) {
        void* p = ws + wo;
        wo = (wo + bytes + 255) & ~(size_t)255;
        return p;
    };
    int* hist   = (int*)alloc((size_t)NK1 * 4);
    int* off    = (int*)alloc((size_t)NK1 * 4);
    int* off2m  = (int*)alloc((size_t)NK1 * 4);
    int* cur    = (int*)alloc((size_t)NK * 4);
    int* part   = (int*)alloc(4096);
    int* edge2  = (int*)alloc((size_t)n_edges * 4);
    short* wtL1 = (short*)alloc((size_t)HDIM * KDIM * 2);
    short* wtL2 = (short*)alloc((size_t)HDIM * KDIM * 2);
    short* h0   = (short*)alloc((size_t)n_ent * HDIM * 2);
    short* h1   = (short*)alloc((size_t)n_ent * HDIM * 2);
    unsigned* srcs = (unsigned*)alloc((size_t)n_ent * NREL * 4);
    // compact AGG: a multi slot needs >=2 edges, so nMulti <= n_edges/2.
    size_t aggMax = (size_t)(n_edges / 2 + 64) * HDIM * 2;   // ~102 MB
    size_t remain = (ws_size > wo) ? ws_size - wo : 0;
    if (aggMax > remain) aggMax = remain;
    short* AGGc = (short*)alloc(aggMax);

    // weight prep + input cast
    compute_wt<<<NREL * HDIM, HDIM, 0, stream>>>(basis1, wc1, wtL1);
    compute_wt<<<NREL * HDIM, HDIM, 0, stream>>>(basis2, wc2, wtL2);
    transposeL<<<HDIM, HDIM, 0, stream>>>(lw1, wtL1);
    transposeL<<<HDIM, HDIM, 0, stream>>>(lw2, wtL2);
    cast_bf16<<<512, 256, 0, stream>>>(emb, h0, n_ent * HDIM / 4);

    // counting sort by key = dst*16+rel (once; reused by both layers)
    zero_i32<<<(NK1 + 255) / 256, 256, 0, stream>>>(hist, NK1);
    hist_k<<<1024, 256, 0, stream>>>(dst, rel, n_edges, hist);
    int nsb = (NK1 + 1023) / 1024;
    scan_p1<<<nsb, 1024, 0, stream>>>(hist, NK1, off, part, 0);
    scan_p2<<<1, 1024, 0, stream>>>(part, nsb);
    scan_p3<<<nsb, 1024, 0, stream>>>(off, part, NK1, NK, cur);
    scatter_k<<<1024, 256, 0, stream>>>(src, dst, rel, n_edges, cur, edge2);
    // compact-index scan: off2m = exclusive scan of (count >= 2)
    scan_p1<<<nsb, 1024, 0, stream>>>(hist, NK1, off2m, part, 2);
    scan_p2<<<1, 1024, 0, stream>>>(part, nsb);
    scan_p3<<<nsb, 1024, 0, stream>>>(off2m, part, NK1, 0, cur);

    int btiles = (n_ent * 2 + 15) / 16;
    int gtiles = (n_ent + 63) / 64;

    // layer 1: h1 = relu([agg|h0] @ Wstack1 + b1)   (bf16 out)
    agg_build<<<btiles, 256, 0, stream>>>(h0, off, off2m, edge2, AGGc, srcs, n_ent);
    agg_gemm<<<gtiles, 256, 0, stream>>>(AGGc, h0, wtL1, srcs, bias1, h1, nullptr, n_ent);
    // layer 2: out = relu([agg|h1] @ Wstack2 + b2)  (fp32 out)
    agg_build<<<btiles, 256, 0, stream>>>(h1, off, off2m, edge2, AGGc, srcs, n_ent);
    agg_gemm<<<gtiles, 256, 0, stream>>>(AGGc, h1, wtL2, srcs, bias2, nullptr, (float*)d_out, n_ent);
}